// Round 11
// baseline (299.843 us; speedup 1.0000x reference)
//
#include <hip/hip_runtime.h>
#include <hip/hip_bf16.h>

typedef __attribute__((ext_vector_type(8))) short bf16x8;
typedef __attribute__((ext_vector_type(4))) float floatx4;

constexpr int D_MODEL = 2048;
constexpr int N_HEADS = 32;
constexpr int N_KV    = 8;
constexpr int B_      = 2;
constexpr int T_      = 2048;
constexpr int BT      = B_ * T_;        // 4096
constexpr int NQKV    = 3072;           // 2048 Q + 512 K + 512 V

// Q pre-scale: 1/sqrt(64) * log2(e), folded into QKV-GEMM epilogue so the
// attention inner loop is a bare v_exp (p = 2^s).
constexpr float Q_SCALE = 0.18033688011112042f;

__device__ __forceinline__ unsigned short f2bf(float f) {
    __hip_bfloat16 h = __float2bfloat16(f);
    return *reinterpret_cast<unsigned short*>(&h);
}

// cheap bf16 pack for values known finite & nonnegative (P = exp(s) in [0,1]):
// round-to-nearest (ties away) = (bits + 0x8000) >> 16. Two values -> 1 dword.
__device__ __forceinline__ unsigned bfpack_rn(float a, float b) {
    unsigned ba = __builtin_bit_cast(unsigned, a);
    unsigned bb = __builtin_bit_cast(unsigned, b);
    return ((ba + 0x8000u) >> 16) | ((bb + 0x8000u) & 0xFFFF0000u);
}

// async 16B global->LDS; lds base wave-uniform, lane i lands at base + i*16.
__device__ __forceinline__ void gll16(const void* g, void* l) {
    typedef const __attribute__((address_space(1))) unsigned int* gp_t;
    typedef __attribute__((address_space(3))) unsigned int* lp_t;
    __builtin_amdgcn_global_load_lds((gp_t)g, (lp_t)l, 16, 0, 0);
}

// fused f32->bf16 of [x | Wq | Wk | Wv] into contiguous dst
// (R10 lesson: moving Wo into a 5th contiguous segment grew the workspace
// past its proven 56MB footprint -> likely OOB fault. Wob aliases Wqkv and
// is converted AFTER the QKV GEMM by the separate cvt_bf16 below.)
__global__ __launch_bounds__(256) void cvt_all(
        const float* __restrict__ x,  const float* __restrict__ wq,
        const float* __restrict__ wk, const float* __restrict__ wv,
        unsigned short* __restrict__ dst) {
    size_t i4 = (size_t)blockIdx.x * 256 + threadIdx.x;
    size_t e = i4 * 4;
    const float* src; size_t off;
    if (e < 8388608)        { src = x;  off = 0; }
    else if (e < 12582912)  { src = wq; off = 8388608; }
    else if (e < 13631488)  { src = wk; off = 12582912; }
    else                    { src = wv; off = 13631488; }
    float4 f = *reinterpret_cast<const float4*>(src + (e - off));
    unsigned short u[4] = {f2bf(f.x), f2bf(f.y), f2bf(f.z), f2bf(f.w)};
    reinterpret_cast<uint2*>(dst)[i4] = *reinterpret_cast<const uint2*>(u);
}

__global__ __launch_bounds__(256) void cvt_bf16(
        const float* __restrict__ src, unsigned short* __restrict__ dst, int n4) {
    int i = blockIdx.x * 256 + threadIdx.x;
    if (i < n4) {
        float4 f = reinterpret_cast<const float4*>(src)[i];
        unsigned short u[4] = {f2bf(f.x), f2bf(f.y), f2bf(f.z), f2bf(f.w)};
        reinterpret_cast<uint2*>(dst)[i] = *reinterpret_cast<const uint2*>(u);
    }
}

// ---------------------------------------------------------------------------
// 256x256 8-PHASE pipelined GEMM (faithful T2+T3+T4+T5 port; R8's coarse
// split regressed exactly as m196 predicted -> this is the fine interleave).
// C[M,N] = A[M,K] @ B[N,K]^T. 512 thr = 8 waves (2M x 4N), wave out 128x64,
// BK=64, LDS = 2 parity x 2 half x (A,B) x 16KB = 128 KiB.
// Iteration i computes K-tiles 2i (parity 0, phases 0-3) and 2i+1 (parity 1,
// phases 4-7). Per phase: {ds_read subtile || stage 1 half-tile (2 gll16)} ->
// barrier -> 16 MFMA -> lgkm0+schedbar -> barrier. Stage rotation (each
// target's last reader finished >=1 phase-barrier earlier):
//   ph0: A(2i+1)lo->AL1   ph1: A(2i+1)hi->AH1   ph2: B(2i+2)lo->BL0
//   ph3: B(2i+2)hi->BH0   ph4: A(2i+2)lo->AL0   ph5: A(2i+2)hi->AH0
//   ph6: B(2i+3)lo->BL1   ph7: B(2i+3)hi->BH1
// vmcnt(4) at ph3/ph7 (allow only the 2 newest stages in flight) gates the
// next tile's reads; last iteration uses vmcnt(0) at ph3 (underflow guard).
// Hazard audit (R10 post-mortem): barriers wave-uniform; per-thread vmcnt
// accounting exact at every gate; every stage target WAR-separated by
// lgkm0+schedbar+barrier from its last reader.
// ---------------------------------------------------------------------------
#define PH_PRE  asm volatile("" ::: "memory");                      \
                __builtin_amdgcn_s_barrier();                       \
                asm volatile("" ::: "memory")
#define PH_POST asm volatile("s_waitcnt lgkmcnt(0)" ::: "memory");  \
                __builtin_amdgcn_sched_barrier(0);                  \
                __builtin_amdgcn_s_barrier();                       \
                asm volatile("" ::: "memory")
#define QUAD(m0, A00, A01, A10, A11)                                          \
    __builtin_amdgcn_s_setprio(1);                                            \
    _Pragma("unroll")                                                         \
    for (int nf = 0; nf < 4; nf++) {                                          \
        acc[m0][nf] = __builtin_amdgcn_mfma_f32_16x16x32_bf16(                \
            A00, bfr[nf][0], acc[m0][nf], 0, 0, 0);                           \
        acc[m0][nf] = __builtin_amdgcn_mfma_f32_16x16x32_bf16(                \
            A01, bfr[nf][1], acc[m0][nf], 0, 0, 0);                           \
        acc[m0 + 1][nf] = __builtin_amdgcn_mfma_f32_16x16x32_bf16(            \
            A10, bfr[nf][0], acc[m0 + 1][nf], 0, 0, 0);                       \
        acc[m0 + 1][nf] = __builtin_amdgcn_mfma_f32_16x16x32_bf16(            \
            A11, bfr[nf][1], acc[m0 + 1][nf], 0, 0, 0);                       \
    }                                                                         \
    __builtin_amdgcn_s_setprio(0)

template<bool SCALEQ, bool FUSEV>
__global__ __launch_bounds__(512, 2) void gemm256p(
        const unsigned short* __restrict__ A,
        const unsigned short* __restrict__ Bb,
        unsigned short* __restrict__ Cp,
        unsigned short* __restrict__ Vtp,
        int M, int N, int K) {
    __shared__ unsigned short As[2][2][128 * 64];   // [parity][half]
    __shared__ unsigned short Bs[2][2][128 * 64];
    const int t = threadIdx.x;
    const int wave = t >> 6, lane = t & 63;
    const int l16 = lane & 15, quad = lane >> 4;
    const int wm  = wave & 1;                       // A half this wave reads
    const int wn  = (wave >> 1) * 64;               // 0,64,128,192
    const int bhf = wn >> 7;                        // B half this wave reads
    const int bro = wn & 64;                        // row offset in B half

    const int gx = gridDim.x;
    int bid = blockIdx.y * gx + blockIdx.x;
    const int cpx = (gx * gridDim.y) >> 3;          // nwg%8==0 (192)
    bid = (bid & 7) * cpx + (bid >> 3);
    const int mtile = (bid / gx) * 256, ntile = (bid % gx) * 256;

    // per-thread staging geometry: one half-tile (128x64) = 2 gll16/thread
    const int sr0 = t >> 3, sr1 = 64 + sr0;
    const int sk0 = (t & 7) ^ (sr0 & 7), sk1 = (t & 7) ^ (sr1 & 7);

    auto stageA = [&](int kt, int half, int d) {
        const unsigned short* base = A + (size_t)(mtile + half * 128) * K + kt * 64;
        gll16(base + (size_t)sr0 * K + sk0 * 8, &As[d][half][wave * 512]);
        gll16(base + (size_t)sr1 * K + sk1 * 8, &As[d][half][(8 + wave) * 512]);
    };
    auto stageB = [&](int kt, int half, int d) {
        const unsigned short* base = Bb + (size_t)(ntile + half * 128) * K + kt * 64;
        gll16(base + (size_t)sr0 * K + sk0 * 8, &Bs[d][half][wave * 512]);
        gll16(base + (size_t)sr1 * K + sk1 * 8, &Bs[d][half][(8 + wave) * 512]);
    };
    auto rdA = [&](int d, int mf, int kc) -> bf16x8 {
        int r = mf * 16 + l16;
        return *reinterpret_cast<const bf16x8*>(
            &As[d][wm][(r * 8 + ((kc * 4 + quad) ^ (r & 7))) * 8]);
    };
    auto rdB = [&](int d, int nf, int kc) -> bf16x8 {
        int r = bro + nf * 16 + l16;
        return *reinterpret_cast<const bf16x8*>(
            &Bs[d][bhf][(r * 8 + ((kc * 4 + quad) ^ (r & 7))) * 8]);
    };

    floatx4 acc[8][4] = {};
    const int NKT = K >> 6;                         // 32
    const int NI  = NKT >> 1;                       // 16

    // prologue: B(0), A(0), B(1); allow B(1)'s 4 loads in flight
    stageB(0, 0, 0); stageB(0, 1, 0);
    stageA(0, 0, 0); stageA(0, 1, 0);
    stageB(1, 0, 1); stageB(1, 1, 1);
    asm volatile("s_waitcnt vmcnt(4)" ::: "memory");
    PH_PRE;

    for (int i = 0; i < NI; ++i) {
        const bool nl = (i + 1 < NI);
        const int k2 = 2 * i;
        bf16x8 bfr[4][2];

        { // ph0: B(d0) all + A(d0) mf0,1 ; stage A(2i+1)lo -> AL1
#pragma unroll
            for (int nf = 0; nf < 4; nf++) {
                bfr[nf][0] = rdB(0, nf, 0); bfr[nf][1] = rdB(0, nf, 1);
            }
            bf16x8 a00 = rdA(0, 0, 0), a01 = rdA(0, 0, 1);
            bf16x8 a10 = rdA(0, 1, 0), a11 = rdA(0, 1, 1);
            stageA(k2 + 1, 0, 1);
            PH_PRE; QUAD(0, a00, a01, a10, a11); PH_POST;
        }
        { // ph1: A(d0) mf2,3 ; stage A(2i+1)hi -> AH1
            bf16x8 a00 = rdA(0, 2, 0), a01 = rdA(0, 2, 1);
            bf16x8 a10 = rdA(0, 3, 0), a11 = rdA(0, 3, 1);
            stageA(k2 + 1, 1, 1);
            PH_PRE; QUAD(2, a00, a01, a10, a11); PH_POST;
        }
        { // ph2: A(d0) mf4,5 ; stage B(2i+2)lo -> BL0 (free since ph0)
            bf16x8 a00 = rdA(0, 4, 0), a01 = rdA(0, 4, 1);
            bf16x8 a10 = rdA(0, 5, 0), a11 = rdA(0, 5, 1);
            if (nl) stageB(k2 + 2, 0, 0);
            PH_PRE; QUAD(4, a00, a01, a10, a11); PH_POST;
        }
        { // ph3: A(d0) mf6,7 ; stage B(2i+2)hi -> BH0 ; TILE GATE
            bf16x8 a00 = rdA(0, 6, 0), a01 = rdA(0, 6, 1);
            bf16x8 a10 = rdA(0, 7, 0), a11 = rdA(0, 7, 1);
            if (nl) {
                stageB(k2 + 2, 1, 0);
                asm volatile("s_waitcnt vmcnt(4)" ::: "memory");
            } else {
                asm volatile("s_waitcnt vmcnt(0)" ::: "memory");
            }
            PH_PRE; QUAD(6, a00, a01, a10, a11); PH_POST;
        }
        { // ph4: B(d1) all + A(d1) mf0,1 ; stage A(2i+2)lo -> AL0
#pragma unroll
            for (int nf = 0; nf < 4; nf++) {
                bfr[nf][0] = rdB(1, nf, 0); bfr[nf][1] = rdB(1, nf, 1);
            }
            bf16x8 a00 = rdA(1, 0, 0), a01 = rdA(1, 0, 1);
            bf16x8 a10 = rdA(1, 1, 0), a11 = rdA(1, 1, 1);
            if (nl) stageA(k2 + 2, 0, 0);
            PH_PRE; QUAD(0, a00, a01, a10, a11); PH_POST;
        }
        { // ph5: A(d1) mf2,3 ; stage A(2i+2)hi -> AH0
            bf16x8 a00 = rdA(1, 2, 0), a01 = rdA(1, 2, 1);
            bf16x8 a10 = rdA(1, 3, 0), a11 = rdA(1, 3, 1);
            if (nl) stageA(k2 + 2, 1, 0);
            PH_PRE; QUAD(2, a00, a01, a10, a11); PH_POST;
        }
        { // ph6: A(d1) mf4,5 ; stage B(2i+3)lo -> BL1 (free since ph4)
            bf16x8 a00 = rdA(1, 4, 0), a01 = rdA(1, 4, 1);
            bf16x8 a10 = rdA(1, 5, 0), a11 = rdA(1, 5, 1);
            if (nl) stageB(k2 + 3, 0, 1);
            PH_PRE; QUAD(4, a00, a01, a10, a11); PH_POST;
        }
        { // ph7: A(d1) mf6,7 ; stage B(2i+3)hi -> BH1 ; TILE GATE
            bf16x8 a00 = rdA(1, 6, 0), a01 = rdA(1, 6, 1);
            bf16x8 a10 = rdA(1, 7, 0), a11 = rdA(1, 7, 1);
            if (nl) stageB(k2 + 3, 1, 1);
            asm volatile("s_waitcnt vmcnt(4)" ::: "memory");
            PH_PRE; QUAD(6, a00, a01, a10, a11); PH_POST;
        }
    }

    float cscale = (SCALEQ && ntile < 2048) ? Q_SCALE : 1.0f;
#pragma unroll
    for (int i = 0; i < 8; i++)
#pragma unroll
        for (int jn = 0; jn < 4; jn++) {
            int col = ntile + wn + jn * 16 + l16;
#pragma unroll
            for (int r = 0; r < 4; r++) {
                int row = mtile + wm * 128 + i * 16 + quad * 4 + r;
                unsigned short v = f2bf(acc[i][jn][r] * cscale);
                Cp[(size_t)row * N + col] = v;
                if constexpr (FUSEV)
                    if (col >= 2560) {
                        int d = col - 2560;              // 0..511
                        int gg = d >> 6, dd = d & 63;
                        int bb = row >> 11, tok = row & 2047;
                        Vtp[(((size_t)bb * 8 + gg) * 64 + dd) * T_ + tok] = v;
                    }
            }
        }
}

// C[M,N] = A[M,K] @ B[N,K]^T, bf16 in, 128x128 tile, BK=64, XOR-swizzled LDS,
// T1 XCD swizzle. Used for the output projection (N=2048 at 256^2 would be
// only 128 blocks = 50% CU coverage).
template<bool C_F32, bool SCALEQ>
__global__ __launch_bounds__(256) void gemm128(
        const unsigned short* __restrict__ A,
        const unsigned short* __restrict__ Bb,
        void* __restrict__ Cp,
        int M, int N, int K) {
    __shared__ unsigned short As[128 * 64];
    __shared__ unsigned short Bs[128 * 64];
    const int t = threadIdx.x;
    const int wave = t >> 6, lane = t & 63;
    const int l16 = lane & 15, quad = lane >> 4;
    const int wm = (wave & 1) * 64, wn = (wave >> 1) * 64;

    const int gx = gridDim.x;
    int bid = blockIdx.y * gx + blockIdx.x;
    const int cpx = (gx * gridDim.y) >> 3;
    bid = (bid & 7) * cpx + (bid >> 3);
    const int mtile = (bid / gx) * 128, ntile = (bid % gx) * 128;

    floatx4 acc[4][4] = {};

    for (int k0 = 0; k0 < K; k0 += 64) {
        __syncthreads();
#pragma unroll
        for (int c = 0; c < 4; c++) {
            int s = (c * 4 + wave) * 64 + lane;
            int row = s >> 3, k8 = (s & 7) ^ (row & 7);
            gll16(&A[(size_t)(mtile + row) * K + k0 + k8 * 8], &As[(c * 4 + wave) * 512]);
            gll16(&Bb[(size_t)(ntile + row) * K + k0 + k8 * 8], &Bs[(c * 4 + wave) * 512]);
        }
        __syncthreads();
#pragma unroll
        for (int kc = 0; kc < 2; kc++) {
            bf16x8 af[4], bfr[4];
#pragma unroll
            for (int i = 0; i < 4; i++) {
                int arow = wm + i * 16 + l16;
                af[i] = *reinterpret_cast<const bf16x8*>(
                    &As[(arow * 8 + ((kc * 4 + quad) ^ (arow & 7))) * 8]);
                int brow = wn + i * 16 + l16;
                bfr[i] = *reinterpret_cast<const bf16x8*>(
                    &Bs[(brow * 8 + ((kc * 4 + quad) ^ (brow & 7))) * 8]);
            }
#pragma unroll
            for (int i = 0; i < 4; i++)
#pragma unroll
                for (int jn = 0; jn < 4; jn++)
                    acc[i][jn] = __builtin_amdgcn_mfma_f32_16x16x32_bf16(
                        af[i], bfr[jn], acc[i][jn], 0, 0, 0);
        }
    }
    float cscale = (SCALEQ && ntile < 2048) ? Q_SCALE : 1.0f;
#pragma unroll
    for (int i = 0; i < 4; i++)
#pragma unroll
        for (int jn = 0; jn < 4; jn++) {
            int col = ntile + wn + jn * 16 + l16;
#pragma unroll
            for (int r = 0; r < 4; r++) {
                int row = mtile + wm + i * 16 + quad * 4 + r;
                if constexpr (C_F32)
                    ((float*)Cp)[(size_t)row * N + col] = acc[i][jn][r];
                else
                    ((unsigned short*)Cp)[(size_t)row * N + col] =
                        f2bf(acc[i][jn][r] * cscale);
            }
        }
}

// Flash causal GQA: 512-thread blocks (8 waves), 128-q tile, 16 q-rows/wave,
// TWO 64-key tiles per barrier pair (R9: halved barriers + cross-tile ILP —
// dropped attn out of the top-5).
__global__ __launch_bounds__(512, 4) void attn8(
        const unsigned short* __restrict__ QKV,   // [4096][3072]
        const unsigned short* __restrict__ Vt,    // [16*64][2048]
        unsigned short* __restrict__ O) {         // [4096][2048]
    __shared__ unsigned short Ks[2][64 * 64];     // swizzled [key][dim]
    __shared__ unsigned short Vs[2][64 * 64];     // swizzled [dim][key]
    __shared__ unsigned short Ps[8][16 * 72];     // per-wave P, [q(16)][key 64]
    const int j  = blockIdx.x;                    // 0..7
    const int bh = blockIdx.y;
    const int b = bh >> 5, h = bh & 31;
    const int g = h >> 2;
    const int t = threadIdx.x, wave = t >> 6, lane = t & 63;
    const int l16 = lane & 15, quad = lane >> 4;

    bf16x8 ones;
#pragma unroll
    for (int i = 0; i < 8; i++) ones[i] = (short)0x3F80;   // bf16 1.0

    const int srow = t >> 3;                      // 0..63
    const int sk8  = (t & 7) ^ (srow & 7);        // XOR-swizzled 8-short slot
    const unsigned short* kbase =
        QKV + (size_t)(b * T_ + srow) * NQKV + 2048 + g * 64 + sk8 * 8;
    const unsigned short* vbase =
        Vt + ((size_t)(b * 8 + g) * 64 + srow) * T_ + sk8 * 8;
    unsigned short* kdst0 = &Ks[0][wave * 512];
    unsigned short* vdst0 = &Vs[0][wave * 512];
    unsigned short* kdst1 = &Ks[1][wave * 512];
    unsigned short* vdst1 = &Vs[1][wave * 512];

    for (int pp = 0; pp < 2; pp++) {
        const int qtl = pp ? (15 - j) : j;
        const int q0  = qtl * 128;
        const int qlo = q0 + wave * 16;           // this wave's first q row

        const unsigned short* qptr =
            QKV + (size_t)(b * T_ + qlo + l16) * NQKV + h * 64;
        bf16x8 qf0 = *reinterpret_cast<const bf16x8*>(qptr + quad * 8);
        bf16x8 qf1 = *reinterpret_cast<const bf16x8*>(qptr + 32 + quad * 8);

        floatx4 o[4] = {};
        floatx4 lacc = {};

        const unsigned short* kp = kbase;
        const unsigned short* vp = vbase;

        const int nit = qtl + 1;                  // (2*qtl+2)/2 tile-pairs
        for (int it = 0; it < nit; it++) {
            __syncthreads();
            gll16(kp, kdst0);
            gll16(vp, vdst0);
            gll16(kp + 64 * NQKV, kdst1);
            gll16(vp + 64, vdst1);
            kp += 128 * NQKV;
            vp += 128;
            __syncthreads();

#pragma unroll
            for (int u = 0; u < 2; u++) {
                const int kb = (it * 2 + u) * 64;
                if (kb > qlo + 15) continue;
                const bool needmask = (kb + 63 > qlo);

#pragma unroll
                for (int km = 0; km < 4; km++) {
                    int krow = km * 16 + l16;
                    bf16x8 k0 = *reinterpret_cast<const bf16x8*>(
                        &Ks[u][(krow * 8 + (quad ^ (krow & 7))) * 8]);
                    bf16x8 k1 = *reinterpret_cast<const bf16x8*>(
                        &Ks[u][(krow * 8 + ((4 + quad) ^ (krow & 7))) * 8]);
                    floatx4 z = {};
                    __builtin_amdgcn_s_setprio(1);
                    z = __builtin_amdgcn_mfma_f32_16x16x32_bf16(k0, qf0, z, 0, 0, 0);
                    z = __builtin_amdgcn_mfma_f32_16x16x32_bf16(k1, qf1, z, 0, 0, 0);
                    __builtin_amdgcn_s_setprio(0);
                    float p[4];
#pragma unroll
                    for (int r = 0; r < 4; r++)
                        p[r] = __builtin_amdgcn_exp2f(z[r]);
                    if (needmask) {
                        int qq = qlo + l16;
#pragma unroll
                        for (int r = 0; r < 4; r++)
                            if ((kb + km * 16 + quad * 4 + r) > qq) p[r] = 0.f;
                    }
                    uint2 w;
                    w.x = bfpack_rn(p[0], p[1]);
                    w.y = bfpack_rn(p[2], p[3]);
                    *reinterpret_cast<uint2*>(
                        &Ps[wave][l16 * 72 + km * 16 + quad * 4]) = w;
                }

                bf16x8 pf[2];
                __builtin_amdgcn_s_setprio(1);
#pragma unroll
                for (int ks = 0; ks < 2; ks++)
                    pf[ks] = *reinterpret_cast<const bf16x8*>(
                        &Ps[wave][l16 * 72 + ks * 32 + quad * 8]);
                lacc = __builtin_amdgcn_mfma_f32_16x16x32_bf16(pf[0], ones, lacc, 0, 0, 0);
                lacc = __builtin_amdgcn_mfma_f32_16x16x32_bf16(pf[1], ones, lacc, 0, 0, 0);
#pragma unroll
                for (int dt = 0; dt < 4; dt++) {
                    int vrow = dt * 16 + l16;
                    bf16x8 v0 = *reinterpret_cast<const bf16x8*>(
                        &Vs[u][(vrow * 8 + (quad ^ (vrow & 7))) * 8]);
                    bf16x8 v1 = *reinterpret_cast<const bf16x8*>(
                        &Vs[u][(vrow * 8 + ((4 + quad) ^ (vrow & 7))) * 8]);
                    o[dt] = __builtin_amdgcn_mfma_f32_16x16x32_bf16(pf[0], v0, o[dt], 0, 0, 0);
                    o[dt] = __builtin_amdgcn_mfma_f32_16x16x32_bf16(pf[1], v1, o[dt], 0, 0, 0);
                }
                __builtin_amdgcn_s_setprio(0);
            }
        }

        // epilogue
#pragma unroll
        for (int r = 0; r < 4; r++) {
            float inv = 1.0f / lacc[r];
            int row = b * T_ + qlo + quad * 4 + r;
#pragma unroll
            for (int dt = 0; dt < 4; dt++)
                O[(size_t)row * D_MODEL + h * 64 + dt * 16 + l16] =
                    f2bf(o[dt][r] * inv);
        }
    }
}

extern "C" void kernel_launch(void* const* d_in, const int* in_sizes, int n_in,
                              void* d_out, int out_size, void* d_ws, size_t ws_size,
                              hipStream_t stream) {
    const float* x  = (const float*)d_in[0];
    const float* Wq = (const float*)d_in[1];
    const float* Wk = (const float*)d_in[2];
    const float* Wv = (const float*)d_in[3];
    const float* Wo = (const float*)d_in[4];

    // proven 56MB workspace layout (R10's 64MB layout suspected OOB-crash)
    unsigned short* xb   = (unsigned short*)d_ws;             // [4096][2048]
    unsigned short* Wqkv = xb + (size_t)BT * D_MODEL;         // [3072][2048]
    unsigned short* QKVo = Wqkv + (size_t)NQKV * D_MODEL;     // [4096][3072]
    unsigned short* Vt   = QKVo + (size_t)BT * NQKV;          // [16][64][2048]
    unsigned short* Aw   = xb;                                 // reuse after QKV GEMM
    unsigned short* Wob  = Wqkv;                               // reuse after QKV GEMM

    dim3 blk(256);
    cvt_all<<<dim3(14336), blk, 0, stream>>>(x, Wq, Wk, Wv, xb);
    // fused QKV projection (256^2 8-phase); Q cols pre-scaled; V-region
    // epilogue also writes Vt (transposed) -> no separate vtrans kernel.
    gemm256p<true, true><<<dim3(NQKV / 256, BT / 256), dim3(512), 0, stream>>>(
        xb, Wqkv, QKVo, Vt, BT, NQKV, D_MODEL);
    cvt_bf16<<<dim3(D_MODEL * D_MODEL / 4 / 256), blk, 0, stream>>>(
        Wo, Wob, D_MODEL * D_MODEL / 4);
    attn8<<<dim3(8, B_ * N_HEADS), dim3(512), 0, stream>>>(QKVo, Vt, Aw);
    gemm128<true, false><<<dim3(D_MODEL / 128, BT / 128), blk, 0, stream>>>(
        Aw, Wob, d_out, BT, D_MODEL, D_MODEL);
}

// Round 12
// 277.820 us; speedup vs baseline: 1.0793x; 1.0793x over previous
//
#include <hip/hip_runtime.h>
#include <hip/hip_bf16.h>

typedef __attribute__((ext_vector_type(8))) short bf16x8;
typedef __attribute__((ext_vector_type(4))) float floatx4;

constexpr int D_MODEL = 2048;
constexpr int N_HEADS = 32;
constexpr int N_KV    = 8;
constexpr int B_      = 2;
constexpr int T_      = 2048;
constexpr int BT      = B_ * T_;        // 4096
constexpr int NQKV    = 3072;           // 2048 Q + 512 K + 512 V

// Q pre-scale: 1/sqrt(64) * log2(e), folded into QKV-GEMM epilogue so the
// attention inner loop is a bare v_exp (p = 2^s).
constexpr float Q_SCALE = 0.18033688011112042f;

__device__ __forceinline__ unsigned short f2bf(float f) {
    __hip_bfloat16 h = __float2bfloat16(f);
    return *reinterpret_cast<unsigned short*>(&h);
}

// cheap bf16 pack for values known finite & nonnegative (P = exp(s) in [0,1]):
// round-to-nearest (ties away) = (bits + 0x8000) >> 16. Two values -> 1 dword.
__device__ __forceinline__ unsigned bfpack_rn(float a, float b) {
    unsigned ba = __builtin_bit_cast(unsigned, a);
    unsigned bb = __builtin_bit_cast(unsigned, b);
    return ((ba + 0x8000u) >> 16) | ((bb + 0x8000u) & 0xFFFF0000u);
}

// async 16B global->LDS; lds base wave-uniform, lane i lands at base + i*16.
__device__ __forceinline__ void gll16(const void* g, void* l) {
    typedef const __attribute__((address_space(1))) unsigned int* gp_t;
    typedef __attribute__((address_space(3))) unsigned int* lp_t;
    __builtin_amdgcn_global_load_lds((gp_t)g, (lp_t)l, 16, 0, 0);
}

// fused f32->bf16 of [x | Wq | Wk | Wv] into contiguous dst
__global__ __launch_bounds__(256) void cvt_all(
        const float* __restrict__ x,  const float* __restrict__ wq,
        const float* __restrict__ wk, const float* __restrict__ wv,
        unsigned short* __restrict__ dst) {
    size_t i4 = (size_t)blockIdx.x * 256 + threadIdx.x;
    size_t e = i4 * 4;
    const float* src; size_t off;
    if (e < 8388608)        { src = x;  off = 0; }
    else if (e < 12582912)  { src = wq; off = 8388608; }
    else if (e < 13631488)  { src = wk; off = 12582912; }
    else                    { src = wv; off = 13631488; }
    float4 f = *reinterpret_cast<const float4*>(src + (e - off));
    unsigned short u[4] = {f2bf(f.x), f2bf(f.y), f2bf(f.z), f2bf(f.w)};
    reinterpret_cast<uint2*>(dst)[i4] = *reinterpret_cast<const uint2*>(u);
}

__global__ __launch_bounds__(256) void cvt_bf16(
        const float* __restrict__ src, unsigned short* __restrict__ dst, int n4) {
    int i = blockIdx.x * 256 + threadIdx.x;
    if (i < n4) {
        float4 f = reinterpret_cast<const float4*>(src)[i];
        unsigned short u[4] = {f2bf(f.x), f2bf(f.y), f2bf(f.z), f2bf(f.w)};
        reinterpret_cast<uint2*>(dst)[i] = *reinterpret_cast<const uint2*>(u);
    }
}

// C[M,N] = A[M,K] @ B[N,K]^T, bf16 in, 128x128 tile, BK=64, XOR-swizzled LDS,
// T1 XCD-aware block swizzle (nwg%8==0: 768, 512). PROVEN BEST for this shape:
// both 256^2 pipeline ports lost (R8 coarse: 90us; R11 8-phase: 100us vs 69
// here — at 128KB LDS the 256^2 tile runs 1 block/CU on a 192-block grid, so
// its 64-256 per-block barriers have no co-resident block to hide them).
// FUSEV: V-region cols also write Vt[bg][d][tok] (replaces vtrans kernel).
template<bool C_F32, bool SCALEQ, bool FUSEV>
__global__ __launch_bounds__(256) void gemm128(
        const unsigned short* __restrict__ A,
        const unsigned short* __restrict__ Bb,
        void* __restrict__ Cp,
        unsigned short* __restrict__ Vtp,
        int M, int N, int K) {
    __shared__ unsigned short As[128 * 64];
    __shared__ unsigned short Bs[128 * 64];
    const int t = threadIdx.x;
    const int wave = t >> 6, lane = t & 63;
    const int l16 = lane & 15, quad = lane >> 4;
    const int wm = (wave & 1) * 64, wn = (wave >> 1) * 64;

    const int gx = gridDim.x;
    int bid = blockIdx.y * gx + blockIdx.x;
    const int cpx = (gx * gridDim.y) >> 3;        // blocks per XCD
    bid = (bid & 7) * cpx + (bid >> 3);           // bijective XCD chunking
    const int mtile = (bid / gx) * 128, ntile = (bid % gx) * 128;

    floatx4 acc[4][4] = {};

    for (int k0 = 0; k0 < K; k0 += 64) {
        __syncthreads();
#pragma unroll
        for (int c = 0; c < 4; c++) {
            int s = (c * 4 + wave) * 64 + lane;
            int row = s >> 3, k8 = (s & 7) ^ (row & 7);
            gll16(&A[(size_t)(mtile + row) * K + k0 + k8 * 8], &As[(c * 4 + wave) * 512]);
            gll16(&Bb[(size_t)(ntile + row) * K + k0 + k8 * 8], &Bs[(c * 4 + wave) * 512]);
        }
        __syncthreads();
#pragma unroll
        for (int kc = 0; kc < 2; kc++) {
            bf16x8 af[4], bfr[4];
#pragma unroll
            for (int i = 0; i < 4; i++) {
                int arow = wm + i * 16 + l16;
                af[i] = *reinterpret_cast<const bf16x8*>(
                    &As[(arow * 8 + ((kc * 4 + quad) ^ (arow & 7))) * 8]);
                int brow = wn + i * 16 + l16;
                bfr[i] = *reinterpret_cast<const bf16x8*>(
                    &Bs[(brow * 8 + ((kc * 4 + quad) ^ (brow & 7))) * 8]);
            }
#pragma unroll
            for (int i = 0; i < 4; i++)
#pragma unroll
                for (int jn = 0; jn < 4; jn++)
                    acc[i][jn] = __builtin_amdgcn_mfma_f32_16x16x32_bf16(
                        af[i], bfr[jn], acc[i][jn], 0, 0, 0);
        }
    }
    float cscale = (SCALEQ && ntile < 2048) ? Q_SCALE : 1.0f;
#pragma unroll
    for (int i = 0; i < 4; i++)
#pragma unroll
        for (int jn = 0; jn < 4; jn++) {
            int col = ntile + wn + jn * 16 + l16;
#pragma unroll
            for (int r = 0; r < 4; r++) {
                int row = mtile + wm + i * 16 + quad * 4 + r;
                if constexpr (C_F32) {
                    ((float*)Cp)[(size_t)row * N + col] = acc[i][jn][r];
                } else {
                    unsigned short v = f2bf(acc[i][jn][r] * cscale);
                    ((unsigned short*)Cp)[(size_t)row * N + col] = v;
                    if constexpr (FUSEV)
                        if (col >= 2560) {
                            int d = col - 2560;          // 0..511
                            int gg = d >> 6, dd = d & 63;
                            int bb = row >> 11, tok = row & 2047;
                            Vtp[(((size_t)bb * 8 + gg) * 64 + dd) * T_ + tok] = v;
                        }
                }
            }
        }
}

// Flash causal GQA, MERGED passes (R12): each block owns q-tiles j AND 15-j
// and sweeps K/V ONCE (the shorter pass's keys are a prefix of the longer's).
// Stage steps drop 34 -> 32-2j (mean 25, -26%), barrier pairs likewise; on
// overlapping tiles both q-tiles' chains run per barrier (2x MFMA density,
// independent chains = ILP — the mechanism behind attn8's win). Keeps attn8's
// 2-tiles-per-barrier dbuf (longer nkt = 32-2j always even). Heavy blocks
// (j=0, 16 pairs) dispatch first -> natural LPT scheduling.
__global__ __launch_bounds__(512, 4) void attn9(
        const unsigned short* __restrict__ QKV,   // [4096][3072]
        const unsigned short* __restrict__ Vt,    // [16*64][2048]
        unsigned short* __restrict__ O) {         // [4096][2048]
    __shared__ unsigned short Ks[2][64 * 64];     // swizzled [key][dim]
    __shared__ unsigned short Vs[2][64 * 64];     // swizzled [dim][key]
    __shared__ unsigned short Ps[8][16 * 72];     // per-wave P, [q(16)][key 64]
    const int j  = blockIdx.x;                    // 0..7
    const int bh = blockIdx.y;
    const int b = bh >> 5, h = bh & 31;
    const int g = h >> 2;
    const int t = threadIdx.x, wave = t >> 6, lane = t & 63;
    const int l16 = lane & 15, quad = lane >> 4;

    bf16x8 ones;
#pragma unroll
    for (int i = 0; i < 8; i++) ones[i] = (short)0x3F80;   // bf16 1.0

    // per-thread staging source (512 threads cover one 64x64 K tile + V tile)
    const int srow = t >> 3;                      // 0..63
    const int sk8  = (t & 7) ^ (srow & 7);        // XOR-swizzled 8-short slot
    const unsigned short* kp =
        QKV + (size_t)(b * T_ + srow) * NQKV + 2048 + g * 64 + sk8 * 8;
    const unsigned short* vp =
        Vt + ((size_t)(b * 8 + g) * 64 + srow) * T_ + sk8 * 8;
    unsigned short* kdst0 = &Ks[0][wave * 512];
    unsigned short* vdst0 = &Vs[0][wave * 512];
    unsigned short* kdst1 = &Ks[1][wave * 512];
    unsigned short* vdst1 = &Vs[1][wave * 512];

    const int qloA = j * 128 + wave * 16;         // short-visibility q-tile
    const int qloB = (15 - j) * 128 + wave * 16;  // long-visibility q-tile

    const unsigned short* qpA =
        QKV + (size_t)(b * T_ + qloA + l16) * NQKV + h * 64;
    const unsigned short* qpB =
        QKV + (size_t)(b * T_ + qloB + l16) * NQKV + h * 64;
    bf16x8 qfA0 = *reinterpret_cast<const bf16x8*>(qpA + quad * 8);
    bf16x8 qfA1 = *reinterpret_cast<const bf16x8*>(qpA + 32 + quad * 8);
    bf16x8 qfB0 = *reinterpret_cast<const bf16x8*>(qpB + quad * 8);
    bf16x8 qfB1 = *reinterpret_cast<const bf16x8*>(qpB + 32 + quad * 8);

    floatx4 oA[4] = {}, oB[4] = {};
    floatx4 laccA = {}, laccB = {};

    // one q-tile's contribution from the K/V tile in buffer u
    auto proc = [&](int u, int kb, int qlo, bf16x8 q0, bf16x8 q1,
                    floatx4 (&o)[4], floatx4& lacc) {
        if (kb > qlo + 15) return;                // no visible keys, this wave
        const bool needmask = (kb + 63 > qlo);

        // S^T per 16-key row-block; exp; pack into Ps
#pragma unroll
        for (int km = 0; km < 4; km++) {
            int krow = km * 16 + l16;
            bf16x8 k0 = *reinterpret_cast<const bf16x8*>(
                &Ks[u][(krow * 8 + (quad ^ (krow & 7))) * 8]);
            bf16x8 k1 = *reinterpret_cast<const bf16x8*>(
                &Ks[u][(krow * 8 + ((4 + quad) ^ (krow & 7))) * 8]);
            floatx4 z = {};
            __builtin_amdgcn_s_setprio(1);
            z = __builtin_amdgcn_mfma_f32_16x16x32_bf16(k0, q0, z, 0, 0, 0);
            z = __builtin_amdgcn_mfma_f32_16x16x32_bf16(k1, q1, z, 0, 0, 0);
            __builtin_amdgcn_s_setprio(0);
            float p[4];
#pragma unroll
            for (int r = 0; r < 4; r++)
                p[r] = __builtin_amdgcn_exp2f(z[r]);
            if (needmask) {
                int qq = qlo + l16;
#pragma unroll
                for (int r = 0; r < 4; r++)
                    if ((kb + km * 16 + quad * 4 + r) > qq) p[r] = 0.f;
            }
            uint2 w;
            w.x = bfpack_rn(p[0], p[1]);
            w.y = bfpack_rn(p[2], p[3]);
            *reinterpret_cast<uint2*>(
                &Ps[wave][l16 * 72 + km * 16 + quad * 4]) = w;
        }

        // P fragments (A-layout), l-sum via MFMA, then PV
        bf16x8 pf[2];
        __builtin_amdgcn_s_setprio(1);
#pragma unroll
        for (int ks = 0; ks < 2; ks++)
            pf[ks] = *reinterpret_cast<const bf16x8*>(
                &Ps[wave][l16 * 72 + ks * 32 + quad * 8]);
        lacc = __builtin_amdgcn_mfma_f32_16x16x32_bf16(pf[0], ones, lacc, 0, 0, 0);
        lacc = __builtin_amdgcn_mfma_f32_16x16x32_bf16(pf[1], ones, lacc, 0, 0, 0);
#pragma unroll
        for (int dt = 0; dt < 4; dt++) {
            int vrow = dt * 16 + l16;
            bf16x8 v0 = *reinterpret_cast<const bf16x8*>(
                &Vs[u][(vrow * 8 + (quad ^ (vrow & 7))) * 8]);
            bf16x8 v1 = *reinterpret_cast<const bf16x8*>(
                &Vs[u][(vrow * 8 + ((4 + quad) ^ (vrow & 7))) * 8]);
            o[dt] = __builtin_amdgcn_mfma_f32_16x16x32_bf16(pf[0], v0, o[dt], 0, 0, 0);
            o[dt] = __builtin_amdgcn_mfma_f32_16x16x32_bf16(pf[1], v1, o[dt], 0, 0, 0);
        }
        __builtin_amdgcn_s_setprio(0);
    };

    const int nit = 16 - j;                       // (32-2j)/2 tile-pairs
    for (int it = 0; it < nit; it++) {
        __syncthreads();
        gll16(kp, kdst0);
        gll16(vp, vdst0);
        gll16(kp + 64 * NQKV, kdst1);
        gll16(vp + 64, vdst1);
        kp += 128 * NQKV;
        vp += 128;
        __syncthreads();

#pragma unroll
        for (int u = 0; u < 2; u++) {
            const int kb = (it * 2 + u) * 64;
            proc(u, kb, qloA, qfA0, qfA1, oA, laccA);
            proc(u, kb, qloB, qfB0, qfB1, oB, laccB);
        }
    }

    // epilogue: both q-tiles
#pragma unroll
    for (int r = 0; r < 4; r++) {
        float invA = 1.0f / laccA[r];
        float invB = 1.0f / laccB[r];
        int rowA = b * T_ + qloA + quad * 4 + r;
        int rowB = b * T_ + qloB + quad * 4 + r;
#pragma unroll
        for (int dt = 0; dt < 4; dt++) {
            O[(size_t)rowA * D_MODEL + h * 64 + dt * 16 + l16] =
                f2bf(oA[dt][r] * invA);
            O[(size_t)rowB * D_MODEL + h * 64 + dt * 16 + l16] =
                f2bf(oB[dt][r] * invB);
        }
    }
}

extern "C" void kernel_launch(void* const* d_in, const int* in_sizes, int n_in,
                              void* d_out, int out_size, void* d_ws, size_t ws_size,
                              hipStream_t stream) {
    const float* x  = (const float*)d_in[0];
    const float* Wq = (const float*)d_in[1];
    const float* Wk = (const float*)d_in[2];
    const float* Wv = (const float*)d_in[3];
    const float* Wo = (const float*)d_in[4];

    // proven 56MB workspace layout
    unsigned short* xb   = (unsigned short*)d_ws;             // [4096][2048]
    unsigned short* Wqkv = xb + (size_t)BT * D_MODEL;         // [3072][2048]
    unsigned short* QKVo = Wqkv + (size_t)NQKV * D_MODEL;     // [4096][3072]
    unsigned short* Vt   = QKVo + (size_t)BT * NQKV;          // [16][64][2048]
    unsigned short* Aw   = xb;                                 // reuse after QKV GEMM
    unsigned short* Wob  = Wqkv;                               // reuse after QKV GEMM

    dim3 blk(256);
    cvt_all<<<dim3(14336), blk, 0, stream>>>(x, Wq, Wk, Wv, xb);
    // fused QKV projection; Q cols pre-scaled; V-region epilogue also writes
    // Vt (transposed) -> no separate vtrans kernel.
    gemm128<false, true, true><<<dim3(NQKV / 128, BT / 128), blk, 0, stream>>>(
        xb, Wqkv, QKVo, Vt, BT, NQKV, D_MODEL);
    cvt_bf16<<<dim3(D_MODEL * D_MODEL / 4 / 256), blk, 0, stream>>>(
        Wo, Wob, D_MODEL * D_MODEL / 4);
    attn9<<<dim3(8, B_ * N_HEADS), dim3(512), 0, stream>>>(QKVo, Vt, Aw);
    gemm128<true, false, false><<<dim3(D_MODEL / 128, BT / 128), blk, 0, stream>>>(
        Aw, Wob, d_out, nullptr, BT, D_MODEL, D_MODEL);
}

// Round 15
// 272.559 us; speedup vs baseline: 1.1001x; 1.0193x over previous
//
#include <hip/hip_runtime.h>
#include <hip/hip_bf16.h>

typedef __attribute__((ext_vector_type(8))) short bf16x8;
typedef __attribute__((ext_vector_type(4))) float floatx4;

constexpr int D_MODEL = 2048;
constexpr int N_HEADS = 32;
constexpr int N_KV    = 8;
constexpr int B_      = 2;
constexpr int T_      = 2048;
constexpr int BT      = B_ * T_;        // 4096
constexpr int NQKV    = 3072;           // 2048 Q + 512 K + 512 V

// Q pre-scale: 1/sqrt(64) * log2(e), folded into QKV-GEMM epilogue so the
// attention inner loop is a bare v_exp (p = 2^s).
constexpr float Q_SCALE = 0.18033688011112042f;

__device__ __forceinline__ unsigned short f2bf(float f) {
    __hip_bfloat16 h = __float2bfloat16(f);
    return *reinterpret_cast<unsigned short*>(&h);
}

// cheap bf16 pack for values known finite & nonnegative (P = exp(s) in [0,1]):
// round-to-nearest (ties away) = (bits + 0x8000) >> 16. Two values -> 1 dword.
__device__ __forceinline__ unsigned bfpack_rn(float a, float b) {
    unsigned ba = __builtin_bit_cast(unsigned, a);
    unsigned bb = __builtin_bit_cast(unsigned, b);
    return ((ba + 0x8000u) >> 16) | ((bb + 0x8000u) & 0xFFFF0000u);
}

// async 16B global->LDS; lds base wave-uniform, lane i lands at base + i*16.
__device__ __forceinline__ void gll16(const void* g, void* l) {
    typedef const __attribute__((address_space(1))) unsigned int* gp_t;
    typedef __attribute__((address_space(3))) unsigned int* lp_t;
    __builtin_amdgcn_global_load_lds((gp_t)g, (lp_t)l, 16, 0, 0);
}

// fused f32->bf16 of [x | Wq | Wk | Wv] into contiguous dst
__global__ __launch_bounds__(256) void cvt_all(
        const float* __restrict__ x,  const float* __restrict__ wq,
        const float* __restrict__ wk, const float* __restrict__ wv,
        unsigned short* __restrict__ dst) {
    size_t i4 = (size_t)blockIdx.x * 256 + threadIdx.x;
    size_t e = i4 * 4;
    const float* src; size_t off;
    if (e < 8388608)        { src = x;  off = 0; }
    else if (e < 12582912)  { src = wq; off = 8388608; }
    else if (e < 13631488)  { src = wk; off = 12582912; }
    else                    { src = wv; off = 13631488; }
    float4 f = *reinterpret_cast<const float4*>(src + (e - off));
    unsigned short u[4] = {f2bf(f.x), f2bf(f.y), f2bf(f.z), f2bf(f.w)};
    reinterpret_cast<uint2*>(dst)[i4] = *reinterpret_cast<const uint2*>(u);
}

__global__ __launch_bounds__(256) void cvt_bf16(
        const float* __restrict__ src, unsigned short* __restrict__ dst, int n4) {
    int i = blockIdx.x * 256 + threadIdx.x;
    if (i < n4) {
        float4 f = reinterpret_cast<const float4*>(src)[i];
        unsigned short u[4] = {f2bf(f.x), f2bf(f.y), f2bf(f.z), f2bf(f.w)};
        reinterpret_cast<uint2*>(dst)[i] = *reinterpret_cast<const uint2*>(u);
    }
}

// C[M,N] = A[M,K] @ B[N,K]^T, bf16 in, 128x128 tile, BK=64, XOR-swizzled LDS,
// T1 XCD-aware block swizzle (nwg%8==0: 768, 512). PROVEN BEST for this shape:
// both 256^2 pipeline ports lost (R8 coarse: 90us; R11 8-phase: 100us vs 67
// here — at 128KB LDS the 256^2 tile runs 1 block/CU on a 192-block grid, so
// its 64-256 per-block barriers have no co-resident block to hide them).
// NOTE: in-loop staging address recompute is INTENTIONAL — the hoisted-pointer
// variant was implicated in two container failures (R13/R14 A/B); predicted
// upside was ~0 anyway (VALU co-issues under MFMA).
// FUSEV: V-region cols also write Vt[bg][d][tok] (replaces vtrans kernel).
template<bool C_F32, bool SCALEQ, bool FUSEV>
__global__ __launch_bounds__(256) void gemm128(
        const unsigned short* __restrict__ A,
        const unsigned short* __restrict__ Bb,
        void* __restrict__ Cp,
        unsigned short* __restrict__ Vtp,
        int M, int N, int K) {
    __shared__ unsigned short As[128 * 64];
    __shared__ unsigned short Bs[128 * 64];
    const int t = threadIdx.x;
    const int wave = t >> 6, lane = t & 63;
    const int l16 = lane & 15, quad = lane >> 4;
    const int wm = (wave & 1) * 64, wn = (wave >> 1) * 64;

    const int gx = gridDim.x;
    int bid = blockIdx.y * gx + blockIdx.x;
    const int cpx = (gx * gridDim.y) >> 3;        // blocks per XCD
    bid = (bid & 7) * cpx + (bid >> 3);           // bijective XCD chunking
    const int mtile = (bid / gx) * 128, ntile = (bid % gx) * 128;

    floatx4 acc[4][4] = {};

    for (int k0 = 0; k0 < K; k0 += 64) {
        __syncthreads();
#pragma unroll
        for (int c = 0; c < 4; c++) {
            int s = (c * 4 + wave) * 64 + lane;
            int row = s >> 3, k8 = (s & 7) ^ (row & 7);
            gll16(&A[(size_t)(mtile + row) * K + k0 + k8 * 8], &As[(c * 4 + wave) * 512]);
            gll16(&Bb[(size_t)(ntile + row) * K + k0 + k8 * 8], &Bs[(c * 4 + wave) * 512]);
        }
        __syncthreads();
#pragma unroll
        for (int kc = 0; kc < 2; kc++) {
            bf16x8 af[4], bfr[4];
#pragma unroll
            for (int i = 0; i < 4; i++) {
                int arow = wm + i * 16 + l16;
                af[i] = *reinterpret_cast<const bf16x8*>(
                    &As[(arow * 8 + ((kc * 4 + quad) ^ (arow & 7))) * 8]);
                int brow = wn + i * 16 + l16;
                bfr[i] = *reinterpret_cast<const bf16x8*>(
                    &Bs[(brow * 8 + ((kc * 4 + quad) ^ (brow & 7))) * 8]);
            }
#pragma unroll
            for (int i = 0; i < 4; i++)
#pragma unroll
                for (int jn = 0; jn < 4; jn++)
                    acc[i][jn] = __builtin_amdgcn_mfma_f32_16x16x32_bf16(
                        af[i], bfr[jn], acc[i][jn], 0, 0, 0);
        }
    }
    float cscale = (SCALEQ && ntile < 2048) ? Q_SCALE : 1.0f;
#pragma unroll
    for (int i = 0; i < 4; i++)
#pragma unroll
        for (int jn = 0; jn < 4; jn++) {
            int col = ntile + wn + jn * 16 + l16;
#pragma unroll
            for (int r = 0; r < 4; r++) {
                int row = mtile + wm + i * 16 + quad * 4 + r;
                if constexpr (C_F32) {
                    ((float*)Cp)[(size_t)row * N + col] = acc[i][jn][r];
                } else {
                    unsigned short v = f2bf(acc[i][jn][r] * cscale);
                    ((unsigned short*)Cp)[(size_t)row * N + col] = v;
                    if constexpr (FUSEV)
                        if (col >= 2560) {
                            int d = col - 2560;          // 0..511
                            int gg = d >> 6, dd = d & 63;
                            int bb = row >> 11, tok = row & 2047;
                            Vtp[(((size_t)bb * 8 + gg) * 64 + dd) * T_ + tok] = v;
                        }
                }
            }
        }
}

// Flash causal GQA, MERGED passes (R12): each block owns q-tiles j AND 15-j
// and sweeps K/V ONCE (the shorter pass's keys are a prefix of the longer's).
// Stage steps drop 34 -> 32-2j (mean 25, -26%), barrier pairs likewise; on
// overlapping tiles both q-tiles' chains run per barrier (2x MFMA density,
// independent chains = ILP — the mechanism behind attn8's win). Keeps attn8's
// 2-tiles-per-barrier dbuf (longer nkt = 32-2j always even). Heavy blocks
// (j=0, 16 pairs) dispatch first -> natural LPT scheduling.
__global__ __launch_bounds__(512, 4) void attn9(
        const unsigned short* __restrict__ QKV,   // [4096][3072]
        const unsigned short* __restrict__ Vt,    // [16*64][2048]
        unsigned short* __restrict__ O) {         // [4096][2048]
    __shared__ unsigned short Ks[2][64 * 64];     // swizzled [key][dim]
    __shared__ unsigned short Vs[2][64 * 64];     // swizzled [dim][key]
    __shared__ unsigned short Ps[8][16 * 72];     // per-wave P, [q(16)][key 64]
    const int j  = blockIdx.x;                    // 0..7
    const int bh = blockIdx.y;
    const int b = bh >> 5, h = bh & 31;
    const int g = h >> 2;
    const int t = threadIdx.x, wave = t >> 6, lane = t & 63;
    const int l16 = lane & 15, quad = lane >> 4;

    bf16x8 ones;
#pragma unroll
    for (int i = 0; i < 8; i++) ones[i] = (short)0x3F80;   // bf16 1.0

    // per-thread staging source (512 threads cover one 64x64 K tile + V tile)
    const int srow = t >> 3;                      // 0..63
    const int sk8  = (t & 7) ^ (srow & 7);        // XOR-swizzled 8-short slot
    const unsigned short* kp =
        QKV + (size_t)(b * T_ + srow) * NQKV + 2048 + g * 64 + sk8 * 8;
    const unsigned short* vp =
        Vt + ((size_t)(b * 8 + g) * 64 + srow) * T_ + sk8 * 8;
    unsigned short* kdst0 = &Ks[0][wave * 512];
    unsigned short* vdst0 = &Vs[0][wave * 512];
    unsigned short* kdst1 = &Ks[1][wave * 512];
    unsigned short* vdst1 = &Vs[1][wave * 512];

    const int qloA = j * 128 + wave * 16;         // short-visibility q-tile
    const int qloB = (15 - j) * 128 + wave * 16;  // long-visibility q-tile

    const unsigned short* qpA =
        QKV + (size_t)(b * T_ + qloA + l16) * NQKV + h * 64;
    const unsigned short* qpB =
        QKV + (size_t)(b * T_ + qloB + l16) * NQKV + h * 64;
    bf16x8 qfA0 = *reinterpret_cast<const bf16x8*>(qpA + quad * 8);
    bf16x8 qfA1 = *reinterpret_cast<const bf16x8*>(qpA + 32 + quad * 8);
    bf16x8 qfB0 = *reinterpret_cast<const bf16x8*>(qpB + quad * 8);
    bf16x8 qfB1 = *reinterpret_cast<const bf16x8*>(qpB + 32 + quad * 8);

    floatx4 oA[4] = {}, oB[4] = {};
    floatx4 laccA = {}, laccB = {};

    // one q-tile's contribution from the K/V tile in buffer u
    auto proc = [&](int u, int kb, int qlo, bf16x8 q0, bf16x8 q1,
                    floatx4 (&o)[4], floatx4& lacc) {
        if (kb > qlo + 15) return;                // no visible keys, this wave
        const bool needmask = (kb + 63 > qlo);

        // S^T per 16-key row-block; exp; pack into Ps
#pragma unroll
        for (int km = 0; km < 4; km++) {
            int krow = km * 16 + l16;
            bf16x8 k0 = *reinterpret_cast<const bf16x8*>(
                &Ks[u][(krow * 8 + (quad ^ (krow & 7))) * 8]);
            bf16x8 k1 = *reinterpret_cast<const bf16x8*>(
                &Ks[u][(krow * 8 + ((4 + quad) ^ (krow & 7))) * 8]);
            floatx4 z = {};
            __builtin_amdgcn_s_setprio(1);
            z = __builtin_amdgcn_mfma_f32_16x16x32_bf16(k0, q0, z, 0, 0, 0);
            z = __builtin_amdgcn_mfma_f32_16x16x32_bf16(k1, q1, z, 0, 0, 0);
            __builtin_amdgcn_s_setprio(0);
            float p[4];
#pragma unroll
            for (int r = 0; r < 4; r++)
                p[r] = __builtin_amdgcn_exp2f(z[r]);
            if (needmask) {
                int qq = qlo + l16;
#pragma unroll
                for (int r = 0; r < 4; r++)
                    if ((kb + km * 16 + quad * 4 + r) > qq) p[r] = 0.f;
            }
            uint2 w;
            w.x = bfpack_rn(p[0], p[1]);
            w.y = bfpack_rn(p[2], p[3]);
            *reinterpret_cast<uint2*>(
                &Ps[wave][l16 * 72 + km * 16 + quad * 4]) = w;
        }

        // P fragments (A-layout), l-sum via MFMA, then PV
        bf16x8 pf[2];
        __builtin_amdgcn_s_setprio(1);
#pragma unroll
        for (int ks = 0; ks < 2; ks++)
            pf[ks] = *reinterpret_cast<const bf16x8*>(
                &Ps[wave][l16 * 72 + ks * 32 + quad * 8]);
        lacc = __builtin_amdgcn_mfma_f32_16x16x32_bf16(pf[0], ones, lacc, 0, 0, 0);
        lacc = __builtin_amdgcn_mfma_f32_16x16x32_bf16(pf[1], ones, lacc, 0, 0, 0);
#pragma unroll
        for (int dt = 0; dt < 4; dt++) {
            int vrow = dt * 16 + l16;
            bf16x8 v0 = *reinterpret_cast<const bf16x8*>(
                &Vs[u][(vrow * 8 + (quad ^ (vrow & 7))) * 8]);
            bf16x8 v1 = *reinterpret_cast<const bf16x8*>(
                &Vs[u][(vrow * 8 + ((4 + quad) ^ (vrow & 7))) * 8]);
            o[dt] = __builtin_amdgcn_mfma_f32_16x16x32_bf16(pf[0], v0, o[dt], 0, 0, 0);
            o[dt] = __builtin_amdgcn_mfma_f32_16x16x32_bf16(pf[1], v1, o[dt], 0, 0, 0);
        }
        __builtin_amdgcn_s_setprio(0);
    };

    const int nit = 16 - j;                       // (32-2j)/2 tile-pairs
    for (int it = 0; it < nit; it++) {
        __syncthreads();
        gll16(kp, kdst0);
        gll16(vp, vdst0);
        gll16(kp + 64 * NQKV, kdst1);
        gll16(vp + 64, vdst1);
        kp += 128 * NQKV;
        vp += 128;
        __syncthreads();

#pragma unroll
        for (int u = 0; u < 2; u++) {
            const int kb = (it * 2 + u) * 64;
            proc(u, kb, qloA, qfA0, qfA1, oA, laccA);
            proc(u, kb, qloB, qfB0, qfB1, oB, laccB);
        }
    }

    // epilogue: both q-tiles
#pragma unroll
    for (int r = 0; r < 4; r++) {
        float invA = 1.0f / laccA[r];
        float invB = 1.0f / laccB[r];
        int rowA = b * T_ + qloA + quad * 4 + r;
        int rowB = b * T_ + qloB + quad * 4 + r;
#pragma unroll
        for (int dt = 0; dt < 4; dt++) {
            O[(size_t)rowA * D_MODEL + h * 64 + dt * 16 + l16] =
                f2bf(oA[dt][r] * invA);
            O[(size_t)rowB * D_MODEL + h * 64 + dt * 16 + l16] =
                f2bf(oB[dt][r] * invB);
        }
    }
}

extern "C" void kernel_launch(void* const* d_in, const int* in_sizes, int n_in,
                              void* d_out, int out_size, void* d_ws, size_t ws_size,
                              hipStream_t stream) {
    const float* x  = (const float*)d_in[0];
    const float* Wq = (const float*)d_in[1];
    const float* Wk = (const float*)d_in[2];
    const float* Wv = (const float*)d_in[3];
    const float* Wo = (const float*)d_in[4];

    // proven 56MB workspace layout
    unsigned short* xb   = (unsigned short*)d_ws;             // [4096][2048]
    unsigned short* Wqkv = xb + (size_t)BT * D_MODEL;         // [3072][2048]
    unsigned short* QKVo = Wqkv + (size_t)NQKV * D_MODEL;     // [4096][3072]
    unsigned short* Vt   = QKVo + (size_t)BT * NQKV;          // [16][64][2048]
    unsigned short* Aw   = xb;                                 // reuse after QKV GEMM
    unsigned short* Wob  = Wqkv;                               // reuse after QKV GEMM

    dim3 blk(256);
    cvt_all<<<dim3(14336), blk, 0, stream>>>(x, Wq, Wk, Wv, xb);
    // fused QKV projection; Q cols pre-scaled; V-region epilogue also writes
    // Vt (transposed) -> no separate vtrans kernel.
    gemm128<false, true, true><<<dim3(NQKV / 128, BT / 128), blk, 0, stream>>>(
        xb, Wqkv, QKVo, Vt, BT, NQKV, D_MODEL);
    cvt_bf16<<<dim3(D_MODEL * D_MODEL / 4 / 256), blk, 0, stream>>>(
        Wo, Wob, D_MODEL * D_MODEL / 4);
    attn9<<<dim3(8, B_ * N_HEADS), dim3(512), 0, stream>>>(QKVo, Vt, Aw);
    gemm128<true, false, false><<<dim3(D_MODEL / 128, BT / 128), blk, 0, stream>>>(
        Aw, Wob, d_out, nullptr, BT, D_MODEL, D_MODEL);
}